// Round 1
// 132.429 us; speedup vs baseline: 1.0641x; 1.0641x over previous
//
#include <hip/hip_runtime.h>
#include <stdint.h>

#define B 4
#define S 2048
#define E 2048
#define H 128

typedef _Float16 f16;
typedef _Float16 half4 __attribute__((ext_vector_type(4)));
typedef _Float16 half8 __attribute__((ext_vector_type(8)));
typedef float f32x4 __attribute__((ext_vector_type(4)));

// MFMA 16x16x32 f16 (m89/m91):
//   A-frag: lane(quad,lx) holds A[m=lx][k=quad*8+j]
//   B-frag: lane(quad,lx) holds B[k=quad*8+j][n=lx]
//   C/D  : lane(quad,lx) holds D[row=quad*4+reg][col=lx]
// FRAG-LINEAR GLOBAL: frag f = 512 f16 at dst[f*512 + lane*8 .. +8]:
// every frag load/store is one coalesced 1 KB b128 per wave.

// ---------------------------------------------------------------------------
// Kernel 0: W matrices fp32 [128][2048] -> frag-linear f16.
//   WQ -> Wf frag = kc*16 + rt ; WK -> +8 ; WV -> Vf frag = kc*8 + rt
// ---------------------------------------------------------------------------
__global__ __launch_bounds__(256) void cvt_w_kernel(
    const float* __restrict__ WQ, const float* __restrict__ WK,
    const float* __restrict__ WV,
    f16* __restrict__ Wf, f16* __restrict__ Vf)
{
    __shared__ __align__(16) f16 LT[4 * 512];
    const int t   = threadIdx.x;
    const int cc  = blockIdx.x;
    const int rt  = blockIdx.y;
    const int mat = blockIdx.z;
    const float* src = (mat == 0) ? WQ : (mat == 1) ? WK : WV;

#pragma unroll
    for (int i = 0; i < 2; ++i) {
        const int idx = i * 256 + t;
        const int row = idx >> 5;
        const int c4  = idx & 31;
        float4 v = ((const float4*)src)[(size_t)(rt * 16 + row) * (E / 4) + cc * 32 + c4];
        const int e0   = c4 * 4;
        const int kcl  = e0 >> 5;
        const int quad = (e0 >> 3) & 3;
        const int j    = e0 & 7;
        half4 hv;
        hv[0] = (f16)v.x; hv[1] = (f16)v.y; hv[2] = (f16)v.z; hv[3] = (f16)v.w;
        *(half4*)&LT[(kcl * 64 + quad * 16 + row) * 8 + j] = hv;
    }
    __syncthreads();

    const half8 val = *(const half8*)&LT[t * 8];
    const int kcg = cc * 4 + (t >> 6);
    const int ln  = t & 63;
    if (mat == 2) *(half8*)&Vf[((size_t)kcg * 8  + rt)           * 512 + ln * 8] = val;
    else          *(half8*)&Wf[((size_t)kcg * 16 + rt + mat * 8) * 512 + ln * 8] = val;
}

// ---------------------------------------------------------------------------
// Kernel 1 (v2): Q,K projection. 256 blocks x 1024 thr, 32 rows/block,
// full-K X staged in 128 KB LDS (1 block/CU, 4 waves/SIMD).
//   - Wf L2 traffic halved vs v1 (256 blocks x 1MB = 256 MB), 2 MFMA per
//     B-frag load.
//   - Staging fully coalesced (wave = 2 KB contiguous); XOR swizzle
//     m ^= (quad<<1)|(kc&1) spreads transposed frag writes across all 32
//     banks (b128 write at its 8-cyc floor). K-loop read applies the same
//     involution; reads stay linear-contiguous 1KB/wave = conflict-free.
//   - per-block kc rotation de-phases the blocks' identical Wf walk.
// ---------------------------------------------------------------------------
__global__ __launch_bounds__(1024, 4) void proj_kernel(
    const float4* __restrict__ X,      // [B*S][E/4] fp32
    const f16* __restrict__ Wf,
    f16* __restrict__ Qf, f16* __restrict__ Kf)
{
    __shared__ __align__(16) f16 XA[8192 * 8];   // 128 KB; slot = 16B unit
    const int t    = threadIdx.x;
    const int w    = t >> 6;
    const int lane = t & 63;
    const int quad = lane >> 4;
    const int lx   = lane & 15;
    const int r0   = blockIdx.x * 32;

    // ---- stage X: 32 rows x 2048 k, fp32 -> f16 frag-linear, coalesced ----
    // pair p = row*256 + c42: thread loads 2 consecutive float4 (8 k-elems =
    // one full j-run of a frag row) -> one half8 LDS write.
    float4 xv[16];
#pragma unroll
    for (int i = 0; i < 8; ++i) {
        const int p   = i * 1024 + t;
        const int row = p >> 8;
        const int c42 = p & 255;
        const float4* xp = &X[(size_t)(r0 + row) * (E / 4) + c42 * 2];
        xv[i * 2]     = xp[0];
        xv[i * 2 + 1] = xp[1];
    }
#pragma unroll
    for (int i = 0; i < 8; ++i) {
        const int p   = i * 1024 + t;
        const int row = p >> 8;
        const int c42 = p & 255;
        const int kc  = c42 >> 2;
        const int qs  = c42 & 3;
        const int rt  = row >> 4;
        const int m   = row & 15;
        const int mp  = m ^ ((qs << 1) | (kc & 1));      // bank swizzle
        half8 hv;
        hv[0] = (f16)xv[i * 2].x;     hv[1] = (f16)xv[i * 2].y;
        hv[2] = (f16)xv[i * 2].z;     hv[3] = (f16)xv[i * 2].w;
        hv[4] = (f16)xv[i * 2 + 1].x; hv[5] = (f16)xv[i * 2 + 1].y;
        hv[6] = (f16)xv[i * 2 + 1].z; hv[7] = (f16)xv[i * 2 + 1].w;
        *(half8*)&XA[(size_t)(kc * 128 + rt * 64 + qs * 16 + mp) * 8] = hv;
    }
    __syncthreads();

    // ---- barrier-free K-loop: 64 x (2 ds_read + 1 global b128 + 2 MFMA) ----
    f32x4 C0 = f32x4{0.f, 0.f, 0.f, 0.f};
    f32x4 C1 = f32x4{0.f, 0.f, 0.f, 0.f};
    const f16* wbase = &Wf[(size_t)w * 512 + lane * 8];     // frag kc*16 + w
    const int rot = blockIdx.x & 63;
#pragma unroll 8
    for (int kk = 0; kk < 64; ++kk) {
        const int kc  = (kk + rot) & 63;
        const int lxs = lx ^ ((quad << 1) | (kc & 1));
        half8 b  = *(const half8*)&wbase[(size_t)kc * 16 * 512];          // L2
        half8 a0 = *(const half8*)&XA[(size_t)(kc * 128      + quad * 16 + lxs) * 8];
        half8 a1 = *(const half8*)&XA[(size_t)(kc * 128 + 64 + quad * 16 + lxs) * 8];
        C0 = __builtin_amdgcn_mfma_f32_16x16x32_f16(a0, b, C0, 0, 0, 0);
        C1 = __builtin_amdgcn_mfma_f32_16x16x32_f16(a1, b, C1, 0, 0, 0);
    }

    // ---- epilogue: C -> LT (target frag layout, reuse XA) -> global ----
    __syncthreads();                      // all XA reads done; alias as LT
    f16* LT = XA;                         // 16 frags = 16 KB
    {
        const int qt2 = (w & 1) * 2 + (lx >> 3);
        const int jt  = lx & 7;
        const int fl  = w >> 1;           // 0..7: (mat,hc)
#pragma unroll
        for (int reg = 0; reg < 4; ++reg) {
            LT[(size_t)((fl      * 64) + qt2 * 16 + quad * 4 + reg) * 8 + jt] = (f16)C0[reg];
            LT[(size_t)(((fl + 8) * 64) + qt2 * 16 + quad * 4 + reg) * 8 + jt] = (f16)C1[reg];
        }
    }
    __syncthreads();
    {
        const int f  = t >> 6;            // 0..15: rt = f>>3, idx = f&7
        const int ln = t & 63;
        const half8 v = *(const half8*)&LT[(size_t)f * 512 + ln * 8];
        const int rt  = f >> 3;
        const int hc  = f & 3;
        const int mat = (f >> 2) & 1;
        f16* dst = mat ? Kf : Qf;
        *(half8*)&dst[((size_t)(blockIdx.x * 2 + rt) * 4 + hc) * 512 + ln * 8] = v;
    }
}

// ---------------------------------------------------------------------------
// Kernel 2: attention (unchanged). 512 blocks x 512 thr (4/SIMD).
// Wave = (parity, k-slice); fixed-max softmax -> order-free chunk sums;
// barrier-free k-loop; 8-step O/l combine epilogue.
// ---------------------------------------------------------------------------
__global__ __launch_bounds__(512, 4) void attn_kernel(
    const f16* __restrict__ Qf, const f16* __restrict__ Kf,
    const f16* __restrict__ Vf,
    float* __restrict__ out)
{
    __shared__ __align__(16) f16 PL[8 * 512];
    __shared__ float Obuf[16][132];
    __shared__ float lred[8][16];

    const int t    = threadIdx.x;
    const int w    = t >> 6;
    const int lane = t & 63;
    const int quad = lane >> 4;
    const int lx   = lane & 15;
    const int par  = w >> 2;
    const int wg   = w & 3;
    const int qi   = blockIdx.x & 127;
    const int b    = blockIdx.x >> 7;
    const int qt   = (qi & 1) ? (127 - (qi >> 1)) : (qi >> 1);
    const int q0   = qt * 16;
    const int tb   = b * 128;

    half8 qa[4];
#pragma unroll
    for (int hc = 0; hc < 4; ++hc)
        qa[hc] = *(const half8*)&Qf[(((size_t)(tb + qt)) * 4 + hc) * 512 + lane * 8];

    f32x4 O[8];
#pragma unroll
    for (int hb = 0; hb < 8; ++hb) O[hb] = f32x4{0.f, 0.f, 0.f, 0.f};
    float lp[4] = {0.f, 0.f, 0.f, 0.f};

    const int nch = (qt >> 3) + 1;
    for (int c = par; c < nch; c += 2) {
        half8 kb[8], vb[8];
        const f16* kp = &Kf[((size_t)(tb + c * 8 + wg * 2)) * 4 * 512 + lane * 8];
#pragma unroll
        for (int i = 0; i < 8; ++i) kb[i] = *(const half8*)&kp[(size_t)i * 512];
        const f16* vp = &Vf[((size_t)(c * 4 + wg)) * 8 * 512 + lane * 8];
#pragma unroll
        for (int i = 0; i < 8; ++i) vb[i] = *(const half8*)&vp[(size_t)i * 512];

        f32x4 Sc[2];
        Sc[0] = f32x4{0.f, 0.f, 0.f, 0.f};
        Sc[1] = f32x4{0.f, 0.f, 0.f, 0.f};
#pragma unroll
        for (int sbl = 0; sbl < 2; ++sbl)
#pragma unroll
            for (int hc = 0; hc < 4; ++hc)
                Sc[sbl] = __builtin_amdgcn_mfma_f32_16x16x32_f16(
                    qa[hc], kb[sbl * 4 + hc], Sc[sbl], 0, 0, 0);

        const int s0 = c * 128 + wg * 32;
#pragma unroll
        for (int sbl = 0; sbl < 2; ++sbl) {
            const int sg  = s0 + sbl * 16 + lx;
            const int qp2 = sbl * 2 + (lx >> 3);
#pragma unroll
            for (int reg = 0; reg < 4; ++reg) {
                const int q = quad * 4 + reg;
                float p = (sg <= q0 + q)
                          ? __expf(Sc[sbl][reg] * 0.08838834764831845f - 10.0f)
                          : 0.f;
                lp[reg] += p;
                PL[w * 512 + (qp2 * 16 + q) * 8 + (lx & 7)] = (f16)p;
            }
        }

        const half8 pa = *(const half8*)&PL[w * 512 + lane * 8];
#pragma unroll
        for (int hb = 0; hb < 8; ++hb)
            O[hb] = __builtin_amdgcn_mfma_f32_16x16x32_f16(pa, vb[hb], O[hb], 0, 0, 0);
    }

#pragma unroll
    for (int reg = 0; reg < 4; ++reg) {
        float v = lp[reg];
        v += __shfl_xor(v, 1, 64); v += __shfl_xor(v, 2, 64);
        v += __shfl_xor(v, 4, 64); v += __shfl_xor(v, 8, 64);
        if (lx == 0) lred[w][quad * 4 + reg] = v;
    }

    if (w == 0) {
#pragma unroll
        for (int hb = 0; hb < 8; ++hb)
#pragma unroll
            for (int reg = 0; reg < 4; ++reg)
                Obuf[quad * 4 + reg][hb * 16 + lx] = O[hb][reg];
    }
    __syncthreads();
    for (int ww = 1; ww < 8; ++ww) {
        if (w == ww) {
#pragma unroll
            for (int hb = 0; hb < 8; ++hb)
#pragma unroll
                for (int reg = 0; reg < 4; ++reg)
                    Obuf[quad * 4 + reg][hb * 16 + lx] += O[hb][reg];
        }
        __syncthreads();
    }

    {
        const int h = t & 127, qg = t >> 7;
#pragma unroll
        for (int i = 0; i < 4; ++i) {
            const int qrow = qg * 4 + i;
            float l = 0.f;
#pragma unroll
            for (int ww = 0; ww < 8; ++ww) l += lred[ww][qrow];
            out[((size_t)(tb + qt) * 16 + qrow) * 128 + h] = Obuf[qrow][h] / l;
        }
    }
}

extern "C" void kernel_launch(void* const* d_in, const int* in_sizes, int n_in,
                              void* d_out, int out_size, void* d_ws, size_t ws_size,
                              hipStream_t stream) {
    const float4* X  = (const float4*)d_in[0];
    const float*  WQ = (const float*)d_in[1];
    const float*  WK = (const float*)d_in[2];
    const float*  WV = (const float*)d_in[3];

    f16* Wf = (f16*)d_ws;                     // 1024 frags  1 MB
    f16* Vf = Wf + (size_t)1024 * 512;        //  512 frags  0.5 MB
    f16* Qf = Vf + (size_t)512 * 512;         // 2048 frags  2 MB
    f16* Kf = Qf + (size_t)2048 * 512;        // 2048 frags  2 MB

    cvt_w_kernel<<<dim3(16, 8, 3), 256, 0, stream>>>(WQ, WK, WV, Wf, Vf);
    proj_kernel<<<256, 1024, 0, stream>>>(X, Wf, Qf, Kf);
    attn_kernel<<<512, 512, 0, stream>>>(Qf, Kf, Vf, (float*)d_out);
}